// Round 13
// baseline (204.856 us; speedup 1.0000x reference)
//
#include <hip/hip_runtime.h>
#include <math.h>

#define B_   32
#define T_   8192
#define RNN_ 1024
#define ENC_ 512
#define ATT_ 128
#define LOC_ 32
#define K_   31
#define PAD_ 15

typedef __fp16 half2v __attribute__((ext_vector_type(2)));

__device__ __forceinline__ float fdot2(unsigned int a, unsigned int b, float c) {
    return __builtin_amdgcn_fdot2(__builtin_bit_cast(half2v, a),
                                  __builtin_bit_cast(half2v, b), c, false);
}

__device__ __forceinline__ unsigned int packh2(float x, float y) {
    half2v h;
    h.x = (__fp16)x;
    h.y = (__fp16)y;
    return __builtin_bit_cast(unsigned int, h);
}

__device__ __forceinline__ float fast_tanh(float x) {
    x = fminf(15.f, fmaxf(-15.f, x));
    float e = __expf(2.f * x);
    return (e - 1.f) * __builtin_amdgcn_rcpf(e + 1.f);
}

__device__ __forceinline__ float fast_sigmoid(float x) {
    x = fminf(30.f, fmaxf(-30.f, x));
    float e = __expf(-x);
    return __builtin_amdgcn_rcpf(1.f + e);
}

// ---------------- Kernel A: fused weight-prep + query GEMV ----------------
__global__ __launch_bounds__(256) void k_prep_query(const float* __restrict__ queries,
                                                    const float* __restrict__ wq,
                                                    const float* __restrict__ wconv,
                                                    const float* __restrict__ w1,
                                                    float* __restrict__ qout,
                                                    unsigned int* __restrict__ wTh2,
                                                    unsigned int* __restrict__ w1h2) {
    if (blockIdx.x == (B_ * ATT_) / 4) {
        for (int i = threadIdx.x; i < K_ * LOC_; i += blockDim.x) {
            int k = i / LOC_;
            int l = i % LOC_;
            float wp = wconv[l * (2 * K_) + k];
            float wc = wconv[l * (2 * K_) + K_ + k];
            wTh2[i] = packh2(wp, wc);
        }
        for (int i = threadIdx.x; i < ATT_ * (LOC_ / 2); i += blockDim.x) {
            int a = i / (LOC_ / 2);
            int p = i % (LOC_ / 2);
            w1h2[i] = packh2(w1[a * LOC_ + 2 * p], w1[a * LOC_ + 2 * p + 1]);
        }
        return;
    }
    int w    = blockIdx.x * 4 + (threadIdx.x >> 6);
    int lane = threadIdx.x & 63;
    int b = w >> 7, a = w & 127;
    const float4* qrow = (const float4*)(queries + (size_t)b * RNN_);
    const float4* wrow = (const float4*)(wq + (size_t)a * RNN_);
    float acc = 0.f;
#pragma unroll
    for (int i = 0; i < 4; ++i) {
        float4 x = qrow[i * 64 + lane];
        float4 y = wrow[i * 64 + lane];
        acc += x.x * y.x + x.y * y.y + x.z * y.z + x.w * y.w;
    }
#pragma unroll
    for (int off = 32; off; off >>= 1) acc += __shfl_xor(acc, off);
    if (lane == 0) qout[b * ATT_ + a] = acc;
}

// ---------------- Kernel B: fused conv + 1x1 + tanh + score + sigmoid ------------
// R9 structure (VT=1, tile 256, grid 1024, fdot2). Only change: pm is loaded
// wave-wide as float4 (1 KB/wave-load, 4x in-flight bytes) and distributed
// in-register via __shfl + component select. Arithmetic identical to R9.
#define BLK2  256
#define TILE2 256

__global__ __launch_bounds__(256) void k_score(
    const float* __restrict__ pm,              // [B,ATT,T]
    const float* __restrict__ prev,            // [B,T]
    const float* __restrict__ cum,             // [B,T]
    const unsigned char* __restrict__ masks,
    const float* __restrict__ qbuf,            // [B,ATT]
    const unsigned int* __restrict__ wTh2,     // [K][LOC] half2(wp,wc)
    const unsigned int* __restrict__ w1h2,     // [ATT][16] half2 pairs
    const float* __restrict__ wsc,             // [ATT]
    float* __restrict__ pout)                  // [B,T]
{
    __shared__ unsigned int sPC[TILE2 + K_ - 1];   // half2(prev, cum)
    int blk  = blockIdx.x;
    int b    = blk >> 5;
    int tile = blk & 31;
    int tbase = tile * TILE2;
    const float* prow = prev + (size_t)b * T_;
    const float* crow = cum + (size_t)b * T_;
    for (int i = threadIdx.x; i < TILE2 + K_ - 1; i += BLK2) {
        int g = tbase - PAD_ + i;
        bool ok = (g >= 0) && (g < T_);
        float pv = ok ? prow[g] : 0.f;
        float cv = ok ? crow[g] : 0.f;
        sPC[i] = packh2(pv, cv);
    }
    __syncthreads();

    int tid = threadIdx.x;
    int lt = tid;
    int t0 = tbase + lt;

    float loc[LOC_];
#pragma unroll
    for (int l = 0; l < LOC_; ++l) loc[l] = 0.f;

    for (int k = 0; k < K_; ++k) {
        unsigned int pc = sPC[lt + k];
        const uint4* wk4 = (const uint4*)(wTh2 + k * LOC_);
#pragma unroll
        for (int lq = 0; lq < 8; ++lq) {
            uint4 wv = wk4[lq];
            loc[4 * lq + 0] = fdot2(wv.x, pc, loc[4 * lq + 0]);
            loc[4 * lq + 1] = fdot2(wv.y, pc, loc[4 * lq + 1]);
            loc[4 * lq + 2] = fdot2(wv.z, pc, loc[4 * lq + 2]);
            loc[4 * lq + 3] = fdot2(wv.w, pc, loc[4 * lq + 3]);
        }
    }

    unsigned int lh[LOC_ / 2];
#pragma unroll
    for (int i = 0; i < LOC_ / 2; ++i)
        lh[i] = packh2(loc[2 * i], loc[2 * i + 1]);

    // pm distribution setup: lane i of each wave holds tile floats 4i..4i+3;
    // thread (t offset = tid) pulls from lane tid>>2, component tid&3.
    int srcLane = tid >> 2;      // 0..63, within this thread's own wave
    int comp    = tid & 3;

    float score = 0.f;
    const float* pmt = pm + (size_t)b * ATT_ * T_ + tbase + 4 * (tid & 63);
    const float* qb  = qbuf + b * ATT_;
#pragma unroll 2
    for (int a = 0; a < ATT_; ++a) {
        float4 p4 = *(const float4*)(pmt + (size_t)a * T_);
        float v0 = __shfl(p4.x, srcLane, 64);
        float v1 = __shfl(p4.y, srcLane, 64);
        float v2 = __shfl(p4.z, srcLane, 64);
        float v3 = __shfl(p4.w, srcLane, 64);
        float pmv = (comp == 0) ? v0 : (comp == 1) ? v1 : (comp == 2) ? v2 : v3;

        float q   = qb[a];
        float wsa = wsc[a];
        const uint4* wa4 = (const uint4*)(w1h2 + a * (LOC_ / 2));
        float l2a = 0.f, l2b = 0.f;
        uint4 w0 = wa4[0];
        uint4 w1v = wa4[1];
        uint4 w2 = wa4[2];
        uint4 w3 = wa4[3];
        l2a = fdot2(w0.x, lh[0],  l2a);  l2b = fdot2(w1v.x, lh[4],  l2b);
        l2a = fdot2(w0.y, lh[1],  l2a);  l2b = fdot2(w1v.y, lh[5],  l2b);
        l2a = fdot2(w0.z, lh[2],  l2a);  l2b = fdot2(w1v.z, lh[6],  l2b);
        l2a = fdot2(w0.w, lh[3],  l2a);  l2b = fdot2(w1v.w, lh[7],  l2b);
        l2a = fdot2(w2.x, lh[8],  l2a);  l2b = fdot2(w3.x, lh[12], l2b);
        l2a = fdot2(w2.y, lh[9],  l2a);  l2b = fdot2(w3.y, lh[13], l2b);
        l2a = fdot2(w2.z, lh[10], l2a);  l2b = fdot2(w3.z, lh[14], l2b);
        l2a = fdot2(w2.w, lh[11], l2a);  l2b = fdot2(w3.w, lh[15], l2b);
        score += wsa * fast_tanh(q + pmv + l2a + l2b);
    }

    unsigned char m = masks[(size_t)b * T_ + t0];
    float s = m ? -3.0e38f : score;
    pout[(size_t)b * T_ + t0] = fast_sigmoid(s);
}

// ---------------- Kernel C: alignments = prev*p + shift(prev*(1-p)) --------------
__global__ __launch_bounds__(256) void k_align(const float* __restrict__ p,
                                               const float* __restrict__ prev,
                                               float* __restrict__ align) {
    int idx = blockIdx.x * blockDim.x + threadIdx.x;
    int b  = idx / (T_ / 4);
    int t0 = (idx % (T_ / 4)) * 4;
    const float* pr = p + (size_t)b * T_;
    const float* vr = prev + (size_t)b * T_;
    float4 p4 = *(const float4*)(pr + t0);
    float4 v4 = *(const float4*)(vr + t0);
    float pm1 = (t0 > 0) ? pr[t0 - 1] : 0.f;
    float vm1 = (t0 > 0) ? vr[t0 - 1] : 0.f;
    float4 o;
    o.x = v4.x * p4.x + vm1 * (1.f - pm1);
    o.y = v4.y * p4.y + v4.x * (1.f - p4.x);
    o.z = v4.z * p4.z + v4.y * (1.f - p4.y);
    o.w = v4.w * p4.w + v4.z * (1.f - p4.z);
    *(float4*)(align + (size_t)b * T_ + t0) = o;
}

// ---------------- Kernel D: contexts[b,c] = sum_t align[b,t]*mem[b,c,t] ----------
__global__ __launch_bounds__(256) void k_context(const float* __restrict__ mem,
                                                 const float* __restrict__ align,
                                                 float* __restrict__ ctx) {
    int w    = blockIdx.x * 4 + (threadIdx.x >> 6);
    int lane = threadIdx.x & 63;
    int b = w >> 9;   // /512
    int c = w & 511;
    const float4* mrow = (const float4*)(mem + ((size_t)b * ENC_ + c) * T_);
    const float4* arow = (const float4*)(align + (size_t)b * T_);
    float acc0 = 0.f, acc1 = 0.f;
#pragma unroll 8
    for (int i = 0; i < T_ / 256; ++i) {  // 32 iters, 16B/lane each
        float4 m = mrow[i * 64 + lane];
        float4 a = arow[i * 64 + lane];
        if (i & 1)
            acc1 += m.x * a.x + m.y * a.y + m.z * a.z + m.w * a.w;
        else
            acc0 += m.x * a.x + m.y * a.y + m.z * a.z + m.w * a.w;
    }
    float acc = acc0 + acc1;
#pragma unroll
    for (int off = 32; off; off >>= 1) acc += __shfl_xor(acc, off);
    if (lane == 0) ctx[b * ENC_ + c] = acc;
}

extern "C" void kernel_launch(void* const* d_in, const int* in_sizes, int n_in,
                              void* d_out, int out_size, void* d_ws, size_t ws_size,
                              hipStream_t stream) {
    const float* queries = (const float*)d_in[0];
    const float* memories = (const float*)d_in[1];
    const float* pm = (const float*)d_in[2];
    const float* prev = (const float*)d_in[3];
    const float* cum = (const float*)d_in[4];
    const unsigned char* masks = (const unsigned char*)d_in[5];
    const float* w_query = (const float*)d_in[6];
    const float* w_conv = (const float*)d_in[7];
    const float* w_1x1 = (const float*)d_in[8];
    const float* w_score = (const float*)d_in[9];

    float* out_ctx = (float*)d_out;                       // [B,ENC]
    float* out_align = (float*)d_out + (size_t)B_ * ENC_; // [B,T]

    float* ws_q = (float*)d_ws;                        // B*ATT
    float* ws_p = ws_q + B_ * ATT_;                    // B*T
    unsigned int* ws_wTh2 = (unsigned int*)(ws_p + (size_t)B_ * T_);  // K*LOC
    unsigned int* ws_w1h2 = ws_wTh2 + K_ * LOC_ + 32;  // ATT*16

    hipLaunchKernelGGL(k_prep_query, dim3((B_ * ATT_) / 4 + 1), dim3(256), 0, stream,
                       queries, w_query, w_conv, w_1x1, ws_q, ws_wTh2, ws_w1h2);
    hipLaunchKernelGGL(k_score, dim3(B_ * (T_ / TILE2)), dim3(BLK2), 0, stream,
                       pm, prev, cum, masks, ws_q, ws_wTh2, ws_w1h2, w_score, ws_p);
    hipLaunchKernelGGL(k_align, dim3((B_ * T_ / 4) / 256), dim3(256), 0, stream,
                       ws_p, prev, out_align);
    hipLaunchKernelGGL(k_context, dim3((B_ * ENC_) / 4), dim3(256), 0, stream,
                       memories, out_align, out_ctx);
}

// Round 14
// 161.918 us; speedup vs baseline: 1.2652x; 1.2652x over previous
//
#include <hip/hip_runtime.h>
#include <math.h>

#define B_   32
#define T_   8192
#define RNN_ 1024
#define ENC_ 512
#define ATT_ 128
#define LOC_ 32
#define K_   31
#define PAD_ 15

typedef __fp16 half2v __attribute__((ext_vector_type(2)));

__device__ __forceinline__ float fdot2(unsigned int a, unsigned int b, float c) {
    return __builtin_amdgcn_fdot2(__builtin_bit_cast(half2v, a),
                                  __builtin_bit_cast(half2v, b), c, false);
}

__device__ __forceinline__ unsigned int packh2(float x, float y) {
    half2v h;
    h.x = (__fp16)x;
    h.y = (__fp16)y;
    return __builtin_bit_cast(unsigned int, h);
}

__device__ __forceinline__ float fast_tanh(float x) {
    x = fminf(15.f, fmaxf(-15.f, x));
    float e = __expf(2.f * x);
    return (e - 1.f) * __builtin_amdgcn_rcpf(e + 1.f);
}

__device__ __forceinline__ float fast_sigmoid(float x) {
    x = fminf(30.f, fmaxf(-30.f, x));
    float e = __expf(-x);
    return __builtin_amdgcn_rcpf(1.f + e);
}

// ---------------- Kernel A: fused weight-prep + query GEMV ----------------
__global__ __launch_bounds__(256) void k_prep_query(const float* __restrict__ queries,
                                                    const float* __restrict__ wq,
                                                    const float* __restrict__ wconv,
                                                    const float* __restrict__ w1,
                                                    float* __restrict__ qout,
                                                    unsigned int* __restrict__ wTh2,
                                                    unsigned int* __restrict__ w1h2) {
    if (blockIdx.x == (B_ * ATT_) / 4) {
        for (int i = threadIdx.x; i < K_ * LOC_; i += blockDim.x) {
            int k = i / LOC_;
            int l = i % LOC_;
            float wp = wconv[l * (2 * K_) + k];
            float wc = wconv[l * (2 * K_) + K_ + k];
            wTh2[i] = packh2(wp, wc);
        }
        for (int i = threadIdx.x; i < ATT_ * (LOC_ / 2); i += blockDim.x) {
            int a = i / (LOC_ / 2);
            int p = i % (LOC_ / 2);
            w1h2[i] = packh2(w1[a * LOC_ + 2 * p], w1[a * LOC_ + 2 * p + 1]);
        }
        return;
    }
    int w    = blockIdx.x * 4 + (threadIdx.x >> 6);
    int lane = threadIdx.x & 63;
    int b = w >> 7, a = w & 127;
    const float4* qrow = (const float4*)(queries + (size_t)b * RNN_);
    const float4* wrow = (const float4*)(wq + (size_t)a * RNN_);
    float acc = 0.f;
#pragma unroll
    for (int i = 0; i < 4; ++i) {
        float4 x = qrow[i * 64 + lane];
        float4 y = wrow[i * 64 + lane];
        acc += x.x * y.x + x.y * y.y + x.z * y.z + x.w * y.w;
    }
#pragma unroll
    for (int off = 32; off; off >>= 1) acc += __shfl_xor(acc, off);
    if (lane == 0) qout[b * ATT_ + a] = acc;
}

// ---------------- Kernel B: fused conv + 1x1 + tanh + score + sigmoid ------------
// R9 structure. Change vs R9: a-loop unroll 4 with 4 independent score
// accumulators -> 4 pm loads in flight per wave (16 KB/CU, Little's-law match).
#define BLK2  256
#define TILE2 256

__global__ __launch_bounds__(256) void k_score(
    const float* __restrict__ pm,              // [B,ATT,T]
    const float* __restrict__ prev,            // [B,T]
    const float* __restrict__ cum,             // [B,T]
    const unsigned char* __restrict__ masks,
    const float* __restrict__ qbuf,            // [B,ATT]
    const unsigned int* __restrict__ wTh2,     // [K][LOC] half2(wp,wc)
    const unsigned int* __restrict__ w1h2,     // [ATT][16] half2 pairs
    const float* __restrict__ wsc,             // [ATT]
    float* __restrict__ pout)                  // [B,T]
{
    __shared__ unsigned int sPC[TILE2 + K_ - 1];   // half2(prev, cum)
    int blk  = blockIdx.x;
    int b    = blk >> 5;
    int tile = blk & 31;
    int tbase = tile * TILE2;
    const float* prow = prev + (size_t)b * T_;
    const float* crow = cum + (size_t)b * T_;
    for (int i = threadIdx.x; i < TILE2 + K_ - 1; i += BLK2) {
        int g = tbase - PAD_ + i;
        bool ok = (g >= 0) && (g < T_);
        float pv = ok ? prow[g] : 0.f;
        float cv = ok ? crow[g] : 0.f;
        sPC[i] = packh2(pv, cv);
    }
    __syncthreads();

    int lt = threadIdx.x;
    int t0 = tbase + lt;

    float loc[LOC_];
#pragma unroll
    for (int l = 0; l < LOC_; ++l) loc[l] = 0.f;

    for (int k = 0; k < K_; ++k) {
        unsigned int pc = sPC[lt + k];
        const uint4* wk4 = (const uint4*)(wTh2 + k * LOC_);
#pragma unroll
        for (int lq = 0; lq < 8; ++lq) {
            uint4 wv = wk4[lq];
            loc[4 * lq + 0] = fdot2(wv.x, pc, loc[4 * lq + 0]);
            loc[4 * lq + 1] = fdot2(wv.y, pc, loc[4 * lq + 1]);
            loc[4 * lq + 2] = fdot2(wv.z, pc, loc[4 * lq + 2]);
            loc[4 * lq + 3] = fdot2(wv.w, pc, loc[4 * lq + 3]);
        }
    }

    unsigned int lh[LOC_ / 2];
#pragma unroll
    for (int i = 0; i < LOC_ / 2; ++i)
        lh[i] = packh2(loc[2 * i], loc[2 * i + 1]);

    float sc0 = 0.f, sc1 = 0.f, sc2 = 0.f, sc3 = 0.f;  // 4 independent chains
    const float* pmb = pm + (size_t)b * ATT_ * T_ + t0;
    const float* qb  = qbuf + b * ATT_;
#pragma unroll 4
    for (int a = 0; a < ATT_; ++a) {
        float q   = qb[a];
        float wsa = wsc[a];
        const uint4* wa4 = (const uint4*)(w1h2 + a * (LOC_ / 2));
        float pmv = pmb[(size_t)a * T_];
        float l2a = 0.f, l2b = 0.f;
        uint4 w0 = wa4[0];
        uint4 w1v = wa4[1];
        uint4 w2 = wa4[2];
        uint4 w3 = wa4[3];
        l2a = fdot2(w0.x, lh[0],  l2a);  l2b = fdot2(w1v.x, lh[4],  l2b);
        l2a = fdot2(w0.y, lh[1],  l2a);  l2b = fdot2(w1v.y, lh[5],  l2b);
        l2a = fdot2(w0.z, lh[2],  l2a);  l2b = fdot2(w1v.z, lh[6],  l2b);
        l2a = fdot2(w0.w, lh[3],  l2a);  l2b = fdot2(w1v.w, lh[7],  l2b);
        l2a = fdot2(w2.x, lh[8],  l2a);  l2b = fdot2(w3.x, lh[12], l2b);
        l2a = fdot2(w2.y, lh[9],  l2a);  l2b = fdot2(w3.y, lh[13], l2b);
        l2a = fdot2(w2.z, lh[10], l2a);  l2b = fdot2(w3.z, lh[14], l2b);
        l2a = fdot2(w2.w, lh[11], l2a);  l2b = fdot2(w3.w, lh[15], l2b);
        float term = wsa * fast_tanh(q + pmv + l2a + l2b);
        switch (a & 3) {
            case 0: sc0 += term; break;
            case 1: sc1 += term; break;
            case 2: sc2 += term; break;
            default: sc3 += term; break;
        }
    }
    float score = (sc0 + sc1) + (sc2 + sc3);

    unsigned char m = masks[(size_t)b * T_ + t0];
    float s = m ? -3.0e38f : score;
    pout[(size_t)b * T_ + t0] = fast_sigmoid(s);
}

// ---------------- Kernel C: alignments = prev*p + shift(prev*(1-p)) --------------
__global__ __launch_bounds__(256) void k_align(const float* __restrict__ p,
                                               const float* __restrict__ prev,
                                               float* __restrict__ align) {
    int idx = blockIdx.x * blockDim.x + threadIdx.x;
    int b  = idx / (T_ / 4);
    int t0 = (idx % (T_ / 4)) * 4;
    const float* pr = p + (size_t)b * T_;
    const float* vr = prev + (size_t)b * T_;
    float4 p4 = *(const float4*)(pr + t0);
    float4 v4 = *(const float4*)(vr + t0);
    float pm1 = (t0 > 0) ? pr[t0 - 1] : 0.f;
    float vm1 = (t0 > 0) ? vr[t0 - 1] : 0.f;
    float4 o;
    o.x = v4.x * p4.x + vm1 * (1.f - pm1);
    o.y = v4.y * p4.y + v4.x * (1.f - p4.x);
    o.z = v4.z * p4.z + v4.y * (1.f - p4.y);
    o.w = v4.w * p4.w + v4.z * (1.f - p4.z);
    *(float4*)(align + (size_t)b * T_ + t0) = o;
}

// ---------------- Kernel D: contexts[b,c] = sum_t align[b,t]*mem[b,c,t] ----------
__global__ __launch_bounds__(256) void k_context(const float* __restrict__ mem,
                                                 const float* __restrict__ align,
                                                 float* __restrict__ ctx) {
    int w    = blockIdx.x * 4 + (threadIdx.x >> 6);
    int lane = threadIdx.x & 63;
    int b = w >> 9;   // /512
    int c = w & 511;
    const float4* mrow = (const float4*)(mem + ((size_t)b * ENC_ + c) * T_);
    const float4* arow = (const float4*)(align + (size_t)b * T_);
    float acc0 = 0.f, acc1 = 0.f;
#pragma unroll 8
    for (int i = 0; i < T_ / 256; ++i) {  // 32 iters, 16B/lane each
        float4 m = mrow[i * 64 + lane];
        float4 a = arow[i * 64 + lane];
        if (i & 1)
            acc1 += m.x * a.x + m.y * a.y + m.z * a.z + m.w * a.w;
        else
            acc0 += m.x * a.x + m.y * a.y + m.z * a.z + m.w * a.w;
    }
    float acc = acc0 + acc1;
#pragma unroll
    for (int off = 32; off; off >>= 1) acc += __shfl_xor(acc, off);
    if (lane == 0) ctx[b * ENC_ + c] = acc;
}

extern "C" void kernel_launch(void* const* d_in, const int* in_sizes, int n_in,
                              void* d_out, int out_size, void* d_ws, size_t ws_size,
                              hipStream_t stream) {
    const float* queries = (const float*)d_in[0];
    const float* memories = (const float*)d_in[1];
    const float* pm = (const float*)d_in[2];
    const float* prev = (const float*)d_in[3];
    const float* cum = (const float*)d_in[4];
    const unsigned char* masks = (const unsigned char*)d_in[5];
    const float* w_query = (const float*)d_in[6];
    const float* w_conv = (const float*)d_in[7];
    const float* w_1x1 = (const float*)d_in[8];
    const float* w_score = (const float*)d_in[9];

    float* out_ctx = (float*)d_out;                       // [B,ENC]
    float* out_align = (float*)d_out + (size_t)B_ * ENC_; // [B,T]

    float* ws_q = (float*)d_ws;                        // B*ATT
    float* ws_p = ws_q + B_ * ATT_;                    // B*T
    unsigned int* ws_wTh2 = (unsigned int*)(ws_p + (size_t)B_ * T_);  // K*LOC
    unsigned int* ws_w1h2 = ws_wTh2 + K_ * LOC_ + 32;  // ATT*16

    hipLaunchKernelGGL(k_prep_query, dim3((B_ * ATT_) / 4 + 1), dim3(256), 0, stream,
                       queries, w_query, w_conv, w_1x1, ws_q, ws_wTh2, ws_w1h2);
    hipLaunchKernelGGL(k_score, dim3(B_ * (T_ / TILE2)), dim3(BLK2), 0, stream,
                       pm, prev, cum, masks, ws_q, ws_wTh2, ws_w1h2, w_score, ws_p);
    hipLaunchKernelGGL(k_align, dim3((B_ * T_ / 4) / 256), dim3(256), 0, stream,
                       ws_p, prev, out_align);
    hipLaunchKernelGGL(k_context, dim3((B_ * ENC_) / 4), dim3(256), 0, stream,
                       memories, out_align, out_ctx);
}